// Round 3
// baseline (4496.227 us; speedup 1.0000x reference)
//
#include <hip/hip_runtime.h>
#include <math.h>

#define CCH 512
#define HW 4096
#define NN 32768
#define NE 8192

// ws layout (bytes)
#define WS_BT  0                        // Bt: [512][8192] f32 = 16777216
#define WS_ZZ  (16777216)               // zz f32 [32768]
#define WS_IDX (WS_ZZ + 131072)         // final argmin idx [32768] i32
#define WS_WVH (WS_IDX + 131072)        // per-j-split best val [4][32768] f32
#define WS_WIH (WS_WVH + 524288)        // per-j-split best idx [4][32768] i32
#define WS_ACC (WS_WIH + 524288)        // accs[0]=loss num (f64), accs[1]=wsum (f64)

#define SD 132                          // LDS row stride (128 + 4 pad)

// ---------------- K0: transpose codebook [8192,512] -> Bt [512,8192]; zero accumulators
__global__ __launch_bounds__(256) void k_transpose(const float* __restrict__ cb,
                                                   float* __restrict__ Bt,
                                                   double* __restrict__ accs) {
    __shared__ float S[32 * 33];
    int tid = threadIdx.x;
    int lane = tid & 31, r8 = tid >> 5;
    int bj = blockIdx.x & 255, bc = blockIdx.x >> 8;
    int j0 = bj * 32, c0 = bc * 32;
    if (blockIdx.x == 0 && tid == 0) { accs[0] = 0.0; accs[1] = 0.0; }
#pragma unroll
    for (int rr = 0; rr < 4; ++rr) {
        int r = r8 + rr * 8;
        S[r * 33 + lane] = cb[(size_t)(j0 + r) * CCH + c0 + lane];
    }
    __syncthreads();
#pragma unroll
    for (int rr = 0; rr < 4; ++rr) {
        int r = r8 + rr * 8;
        Bt[(size_t)(c0 + r) * NE + j0 + lane] = S[lane * 33 + r];
    }
}

// ---------------- K1: zz[n] = np.sum(zf*zf, axis=1), numpy's exact pairwise tree
__global__ __launch_bounds__(256) void k_zz(const float* __restrict__ z,
                                            float* __restrict__ zz) {
    int t = threadIdx.x;
    int n = blockIdx.x * 256 + t;
    int b = n >> 12, hw = n & 4095;
    const float* zp = z + (size_t)b * CCH * HW + hw;
    float blk[4];
#pragma unroll
    for (int q = 0; q < 4; ++q) {
        float r[8];
#pragma unroll
        for (int j = 0; j < 8; ++j) {
            float v = zp[(size_t)(q * 128 + j) * HW];
            r[j] = __fmul_rn(v, v);
        }
        for (int i = 8; i < 128; i += 8) {
#pragma unroll
            for (int j = 0; j < 8; ++j) {
                float v = zp[(size_t)(q * 128 + i + j) * HW];
                r[j] = __fadd_rn(r[j], __fmul_rn(v, v));
            }
        }
        blk[q] = __fadd_rn(__fadd_rn(__fadd_rn(r[0], r[1]), __fadd_rn(r[2], r[3])),
                           __fadd_rn(__fadd_rn(r[4], r[5]), __fadd_rn(r[6], r[7])));
    }
    zz[n] = __fadd_rn(__fadd_rn(blk[0], blk[1]), __fadd_rn(blk[2], blk[3]));
}

// ---------------- K2: wsum = sum(m==0)
__global__ __launch_bounds__(256) void k_wsum(const float* __restrict__ m,
                                              double* __restrict__ accs) {
    __shared__ int sc[4];
    int tid = threadIdx.x;
    int base = blockIdx.x * 1024;
    int cnt = 0;
#pragma unroll
    for (int k2 = 0; k2 < 4; ++k2) cnt += (m[base + k2 * 256 + tid] == 0.0f) ? 1 : 0;
#pragma unroll
    for (int o = 32; o; o >>= 1) cnt += __shfl_xor(cnt, o);
    if ((tid & 63) == 0) sc[tid >> 6] = cnt;
    __syncthreads();
    if (tid == 0) atomicAdd(&accs[1], (double)(sc[0] + sc[1] + sc[2] + sc[3]));
}

// ---------------- K3: GEMM 128n x 128j block tile, 8x8/thread, j-split x4.
// Per-C-element arithmetic identical to round 2: single ascending-k fp32 fma
// chain of (2*z)·e, then fl32(zz - acc), strict-< first-index argmin.
__global__ __launch_bounds__(256, 4) void k_gemm(const float* __restrict__ z,
                                                 const float* __restrict__ Bt,
                                                 const float* __restrict__ zz,
                                                 float* __restrict__ wvH,
                                                 int* __restrict__ wiH) {
    __shared__ float lds[64 * SD];          // A: 32 x SD, B: 32 x SD
    float* Als = lds;
    float* Bls = lds + 32 * SD;
    int tid = threadIdx.x;
    int tx = tid & 15, ty = tid >> 4;
    int nb = blockIdx.x >> 2, half = blockIdx.x & 3;
    int n0 = nb * 128;
    int b = n0 >> 12, hw0 = n0 & 4095;
    const float* zb = z + (size_t)b * CCH * HW + hw0;
    int l32 = tid & 31, w8 = tid >> 5;

    float zzr[8];
#pragma unroll
    for (int i = 0; i < 4; ++i) {
        zzr[i]     = zz[n0 + ty * 4 + i];
        zzr[4 + i] = zz[n0 + 64 + ty * 4 + i];
    }

    float pv[8];
    int pi[8];
#pragma unroll
    for (int i = 0; i < 8; ++i) { pv[i] = 3.0e38f; pi[i] = 0; }

    for (int jt = 0; jt < 16; ++jt) {
        int e0 = half * 2048 + jt * 128;
        float acc[8][8];
#pragma unroll
        for (int i = 0; i < 8; ++i)
#pragma unroll
            for (int jj = 0; jj < 8; ++jj) acc[i][jj] = 0.0f;

        for (int kc = 0; kc < 16; ++kc) {
            int c0 = kc * 32;
            __syncthreads();
#pragma unroll
            for (int it = 0; it < 4; ++it) {
                int ck = w8 + it * 8;
                float4 v = *(const float4*)&zb[(size_t)(c0 + ck) * HW + l32 * 4];
                v.x *= 2.0f; v.y *= 2.0f; v.z *= 2.0f; v.w *= 2.0f;
                *(float4*)&Als[ck * SD + l32 * 4] = v;
                float4 u = *(const float4*)&Bt[(size_t)(c0 + ck) * NE + e0 + l32 * 4];
                *(float4*)&Bls[ck * SD + l32 * 4] = u;
            }
            __syncthreads();
#pragma unroll 8
            for (int kk = 0; kk < 32; ++kk) {
                float4 a0 = *(const float4*)&Als[kk * SD + ty * 4];
                float4 a1 = *(const float4*)&Als[kk * SD + 64 + ty * 4];
                float4 b0 = *(const float4*)&Bls[kk * SD + tx * 4];
                float4 b1 = *(const float4*)&Bls[kk * SD + 64 + tx * 4];
                float av[8] = {a0.x, a0.y, a0.z, a0.w, a1.x, a1.y, a1.z, a1.w};
                float bv[8] = {b0.x, b0.y, b0.z, b0.w, b1.x, b1.y, b1.z, b1.w};
#pragma unroll
                for (int i = 0; i < 8; ++i)
#pragma unroll
                    for (int jj = 0; jj < 8; ++jj)
                        acc[i][jj] = __fmaf_rn(av[i], bv[jj], acc[i][jj]);
            }
        }
        // epilogue: C = fl32(zz - B); argmin, ascending j per thread, strict <
#pragma unroll
        for (int jj = 0; jj < 8; ++jj) {
            int j = e0 + ((jj < 4) ? (tx * 4 + jj) : (64 + tx * 4 + (jj - 4)));
#pragma unroll
            for (int i = 0; i < 8; ++i) {
                float tt = __fsub_rn(zzr[i], acc[i][jj]);
                if (tt < pv[i]) { pv[i] = tt; pi[i] = j; }
            }
        }
    }

    // cross-thread (tx) reduction per row: smaller value, tie -> smaller index
    __syncthreads();
    float* RV = lds;                 // 128 rows x 16
    int*   RI = (int*)(lds + 2048);
#pragma unroll
    for (int i = 0; i < 8; ++i) {
        int r = (i < 4) ? (ty * 4 + i) : (64 + ty * 4 + (i - 4));
        RV[r * 16 + tx] = pv[i];
        RI[r * 16 + tx] = pi[i];
    }
    __syncthreads();
    if (tid < 128) {
        float v = RV[tid * 16];
        int i1 = RI[tid * 16];
#pragma unroll
        for (int t = 1; t < 16; ++t) {
            float fv = RV[tid * 16 + t];
            int fi = RI[tid * 16 + t];
            if (fv < v || (fv == v && fi < i1)) { v = fv; i1 = fi; }
        }
        int n = n0 + tid;
        wvH[half * NN + n] = v;
        wiH[half * NN + n] = i1;
    }
}

// ---------------- K3b: merge the 4 j-split candidates (ascending j ranges)
__global__ __launch_bounds__(256) void k_merge(const float* __restrict__ wvH,
                                               const int* __restrict__ wiH,
                                               int* __restrict__ widx,
                                               float* __restrict__ out_idx) {
    int n = blockIdx.x * 256 + threadIdx.x;
    float v = wvH[n];
    int i1 = wiH[n];
#pragma unroll
    for (int h = 1; h < 4; ++h) {
        float fv = wvH[h * NN + n];
        int fi = wiH[h * NN + n];
        if (fv < v || (fv == v && fi < i1)) { v = fv; i1 = fi; }
    }
    widx[n] = i1;
    out_idx[n] = (float)i1;
}

// ---------------- K4: gather z_q, write z_q_st = zf + (zq - zf), accumulate loss numerator
__global__ __launch_bounds__(256) void k_out(const float* __restrict__ z,
                                             const float* __restrict__ cb,
                                             const float* __restrict__ m,
                                             const int* __restrict__ widx,
                                             float* __restrict__ out0,
                                             double* __restrict__ accs) {
    __shared__ float T[64 * 65];
    __shared__ float ls[4];
    int tid = threadIdx.x;
    int lhw = tid & 63, grp = tid >> 6;
    int bn = blockIdx.x >> 3, bc = blockIdx.x & 7;
    int n0 = bn * 64, c0 = bc * 64;
    int b = n0 >> 12, hw0 = n0 & 4095;
    const float* zb = z + (size_t)b * CCH * HW + hw0;
#pragma unroll
    for (int i = 0; i < 16; ++i) {
        int cl = grp + 4 * i;
        T[cl * 65 + lhw] = zb[(size_t)(c0 + cl) * HW + lhw];
    }
    __syncthreads();
    float la = 0.0f;
#pragma unroll
    for (int i = 0; i < 16; ++i) {
        int nl = grp + 4 * i;
        int n = n0 + nl;
        float zf = T[lhw * 65 + nl];
        int id = widx[n];
        float zq = cb[(size_t)id * CCH + c0 + lhw];
        float d = zq - zf;
        out0[(size_t)n * CCH + c0 + lhw] = zf + d;
        if (m[n] == 0.0f) la = fmaf(d, d, la);
    }
#pragma unroll
    for (int o = 32; o; o >>= 1) la += __shfl_xor(la, o);
    if ((tid & 63) == 0) ls[tid >> 6] = la;
    __syncthreads();
    if (tid == 0) atomicAdd(&accs[0], (double)(ls[0] + ls[1] + ls[2] + ls[3]));
}

// ---------------- K5: finalize loss = (1 + BETA) * mse
__global__ void k_final(const double* __restrict__ accs, float* __restrict__ outl) {
    double num = accs[0], wsum = accs[1];
    double denom = wsum * 512.0;
    double l1 = num / denom;
    outl[0] = (float)(l1 + 0.25 * l1);
}

extern "C" void kernel_launch(void* const* d_in, const int* in_sizes, int n_in,
                              void* d_out, int out_size, void* d_ws, size_t ws_size,
                              hipStream_t stream) {
    const float* z  = (const float*)d_in[0];
    const float* m  = (const float*)d_in[1];
    const float* cb = (const float*)d_in[2];
    float* out = (float*)d_out;
    char* ws = (char*)d_ws;

    float*  Bt   = (float*)(ws + WS_BT);
    float*  zzp  = (float*)(ws + WS_ZZ);
    int*    widx = (int*)(ws + WS_IDX);
    float*  wvH  = (float*)(ws + WS_WVH);
    int*    wiH  = (int*)(ws + WS_WIH);
    double* accs = (double*)(ws + WS_ACC);

    float* out0    = out;
    float* outLoss = out + 16777216;
    float* outIdx  = out + 16777217;

    hipLaunchKernelGGL(k_transpose, dim3(4096), dim3(256), 0, stream, cb, Bt, accs);
    hipLaunchKernelGGL(k_zz,        dim3(128),  dim3(256), 0, stream, z, zzp);
    hipLaunchKernelGGL(k_wsum,      dim3(32),   dim3(256), 0, stream, m, accs);
    hipLaunchKernelGGL(k_gemm,      dim3(1024), dim3(256), 0, stream, z, Bt, zzp, wvH, wiH);
    hipLaunchKernelGGL(k_merge,     dim3(128),  dim3(256), 0, stream, wvH, wiH, widx, outIdx);
    hipLaunchKernelGGL(k_out,       dim3(4096), dim3(256), 0, stream, z, cb, m, widx, out0, accs);
    hipLaunchKernelGGL(k_final,     dim3(1),    dim3(1),   0, stream, accs, outLoss);
}

// Round 4
// 3528.297 us; speedup vs baseline: 1.2743x; 1.2743x over previous
//
#include <hip/hip_runtime.h>
#include <math.h>

#define CCH 512
#define HW 4096
#define NN 32768
#define NE 8192

// ws layout (bytes)
#define WS_BT  0                        // Bt: [512][8192] f32 = 16777216
#define WS_ZZ  (16777216)               // zz f32 [32768]
#define WS_IDX (WS_ZZ + 131072)         // final argmin idx [32768] i32
#define WS_WVH (WS_IDX + 131072)        // per-j-split best val [4][32768] f32
#define WS_WIH (WS_WVH + 524288)        // per-j-split best idx [4][32768] i32
#define WS_ACC (WS_WIH + 524288)        // accs[0]=loss num (f64), accs[1]=wsum (f64)

#define SD 132                          // LDS row stride (128 + 4 pad)

// ---------------- K0: transpose codebook [8192,512] -> Bt [512,8192]; zero accumulators
__global__ __launch_bounds__(256) void k_transpose(const float* __restrict__ cb,
                                                   float* __restrict__ Bt,
                                                   double* __restrict__ accs) {
    __shared__ float S[32 * 33];
    int tid = threadIdx.x;
    int lane = tid & 31, r8 = tid >> 5;
    int bj = blockIdx.x & 255, bc = blockIdx.x >> 8;
    int j0 = bj * 32, c0 = bc * 32;
    if (blockIdx.x == 0 && tid == 0) { accs[0] = 0.0; accs[1] = 0.0; }
#pragma unroll
    for (int rr = 0; rr < 4; ++rr) {
        int r = r8 + rr * 8;
        S[r * 33 + lane] = cb[(size_t)(j0 + r) * CCH + c0 + lane];
    }
    __syncthreads();
#pragma unroll
    for (int rr = 0; rr < 4; ++rr) {
        int r = r8 + rr * 8;
        Bt[(size_t)(c0 + r) * NE + j0 + lane] = S[lane * 33 + r];
    }
}

// ---------------- K1: zz[n] = np.sum(zf*zf, axis=1), numpy's exact pairwise tree
__global__ __launch_bounds__(256) void k_zz(const float* __restrict__ z,
                                            float* __restrict__ zz) {
    int t = threadIdx.x;
    int n = blockIdx.x * 256 + t;
    int b = n >> 12, hw = n & 4095;
    const float* zp = z + (size_t)b * CCH * HW + hw;
    float blk[4];
#pragma unroll
    for (int q = 0; q < 4; ++q) {
        float r[8];
#pragma unroll
        for (int j = 0; j < 8; ++j) {
            float v = zp[(size_t)(q * 128 + j) * HW];
            r[j] = __fmul_rn(v, v);
        }
        for (int i = 8; i < 128; i += 8) {
#pragma unroll
            for (int j = 0; j < 8; ++j) {
                float v = zp[(size_t)(q * 128 + i + j) * HW];
                r[j] = __fadd_rn(r[j], __fmul_rn(v, v));
            }
        }
        blk[q] = __fadd_rn(__fadd_rn(__fadd_rn(r[0], r[1]), __fadd_rn(r[2], r[3])),
                           __fadd_rn(__fadd_rn(r[4], r[5]), __fadd_rn(r[6], r[7])));
    }
    zz[n] = __fadd_rn(__fadd_rn(blk[0], blk[1]), __fadd_rn(blk[2], blk[3]));
}

// ---------------- K2: wsum = sum(m==0)
__global__ __launch_bounds__(256) void k_wsum(const float* __restrict__ m,
                                              double* __restrict__ accs) {
    __shared__ int sc[4];
    int tid = threadIdx.x;
    int base = blockIdx.x * 1024;
    int cnt = 0;
#pragma unroll
    for (int k2 = 0; k2 < 4; ++k2) cnt += (m[base + k2 * 256 + tid] == 0.0f) ? 1 : 0;
#pragma unroll
    for (int o = 32; o; o >>= 1) cnt += __shfl_xor(cnt, o);
    if ((tid & 63) == 0) sc[tid >> 6] = cnt;
    __syncthreads();
    if (tid == 0) atomicAdd(&accs[1], (double)(sc[0] + sc[1] + sc[2] + sc[3]));
}

// ---------------- K3: GEMM 128n x 128j block tile, 8x8/thread, j-split x4.
// NOTE: no min-waves clause on launch_bounds — round 3's (256,4) capped the
// allocator at 64 VGPRs and spilled the 64-reg acc tile to scratch (655 MB
// WRITE_SIZE). Per-C-element arithmetic identical to round 2: single
// ascending-k fp32 fma chain of (2*z)·e, fl32(zz-acc), strict-< first-index argmin.
__global__ __launch_bounds__(256) void k_gemm(const float* __restrict__ z,
                                              const float* __restrict__ Bt,
                                              const float* __restrict__ zz,
                                              float* __restrict__ wvH,
                                              int* __restrict__ wiH) {
    __shared__ float lds[64 * SD];          // A: 32 x SD, B: 32 x SD
    float* Als = lds;
    float* Bls = lds + 32 * SD;
    int tid = threadIdx.x;
    int tx = tid & 15, ty = tid >> 4;
    int nb = blockIdx.x >> 2, half = blockIdx.x & 3;
    int n0 = nb * 128;
    int b = n0 >> 12, hw0 = n0 & 4095;
    const float* zb = z + (size_t)b * CCH * HW + hw0;
    int l32 = tid & 31, w8 = tid >> 5;

    float zzr[8];
#pragma unroll
    for (int i = 0; i < 4; ++i) {
        zzr[i]     = zz[n0 + ty * 4 + i];
        zzr[4 + i] = zz[n0 + 64 + ty * 4 + i];
    }

    float pv[8];
    int pi[8];
#pragma unroll
    for (int i = 0; i < 8; ++i) { pv[i] = 3.0e38f; pi[i] = 0; }

    for (int jt = 0; jt < 16; ++jt) {
        int e0 = half * 2048 + jt * 128;
        float acc[8][8];
#pragma unroll
        for (int i = 0; i < 8; ++i)
#pragma unroll
            for (int jj = 0; jj < 8; ++jj) acc[i][jj] = 0.0f;

        for (int kc = 0; kc < 16; ++kc) {
            int c0 = kc * 32;
            __syncthreads();
#pragma unroll
            for (int it = 0; it < 4; ++it) {
                int ck = w8 + it * 8;
                float4 v = *(const float4*)&zb[(size_t)(c0 + ck) * HW + l32 * 4];
                v.x *= 2.0f; v.y *= 2.0f; v.z *= 2.0f; v.w *= 2.0f;
                *(float4*)&Als[ck * SD + l32 * 4] = v;
                float4 u = *(const float4*)&Bt[(size_t)(c0 + ck) * NE + e0 + l32 * 4];
                *(float4*)&Bls[ck * SD + l32 * 4] = u;
            }
            __syncthreads();
#pragma unroll 8
            for (int kk = 0; kk < 32; ++kk) {
                float4 a0 = *(const float4*)&Als[kk * SD + ty * 4];
                float4 a1 = *(const float4*)&Als[kk * SD + 64 + ty * 4];
                float4 b0 = *(const float4*)&Bls[kk * SD + tx * 4];
                float4 b1 = *(const float4*)&Bls[kk * SD + 64 + tx * 4];
                float av[8] = {a0.x, a0.y, a0.z, a0.w, a1.x, a1.y, a1.z, a1.w};
                float bv[8] = {b0.x, b0.y, b0.z, b0.w, b1.x, b1.y, b1.z, b1.w};
#pragma unroll
                for (int i = 0; i < 8; ++i)
#pragma unroll
                    for (int jj = 0; jj < 8; ++jj)
                        acc[i][jj] = __fmaf_rn(av[i], bv[jj], acc[i][jj]);
            }
        }
        // epilogue: C = fl32(zz - B); argmin, ascending j per thread, strict <
#pragma unroll
        for (int jj = 0; jj < 8; ++jj) {
            int j = e0 + ((jj < 4) ? (tx * 4 + jj) : (64 + tx * 4 + (jj - 4)));
#pragma unroll
            for (int i = 0; i < 8; ++i) {
                float tt = __fsub_rn(zzr[i], acc[i][jj]);
                if (tt < pv[i]) { pv[i] = tt; pi[i] = j; }
            }
        }
    }

    // cross-thread (tx) reduction per row: smaller value, tie -> smaller index
    __syncthreads();
    float* RV = lds;                 // 128 rows x 16
    int*   RI = (int*)(lds + 2048);
#pragma unroll
    for (int i = 0; i < 8; ++i) {
        int r = (i < 4) ? (ty * 4 + i) : (64 + ty * 4 + (i - 4));
        RV[r * 16 + tx] = pv[i];
        RI[r * 16 + tx] = pi[i];
    }
    __syncthreads();
    if (tid < 128) {
        float v = RV[tid * 16];
        int i1 = RI[tid * 16];
#pragma unroll
        for (int t = 1; t < 16; ++t) {
            float fv = RV[tid * 16 + t];
            int fi = RI[tid * 16 + t];
            if (fv < v || (fv == v && fi < i1)) { v = fv; i1 = fi; }
        }
        int n = n0 + tid;
        wvH[half * NN + n] = v;
        wiH[half * NN + n] = i1;
    }
}

// ---------------- K3b: merge the 4 j-split candidates (ascending j ranges)
__global__ __launch_bounds__(256) void k_merge(const float* __restrict__ wvH,
                                               const int* __restrict__ wiH,
                                               int* __restrict__ widx,
                                               float* __restrict__ out_idx) {
    int n = blockIdx.x * 256 + threadIdx.x;
    float v = wvH[n];
    int i1 = wiH[n];
#pragma unroll
    for (int h = 1; h < 4; ++h) {
        float fv = wvH[h * NN + n];
        int fi = wiH[h * NN + n];
        if (fv < v || (fv == v && fi < i1)) { v = fv; i1 = fi; }
    }
    widx[n] = i1;
    out_idx[n] = (float)i1;
}

// ---------------- K4: gather z_q, write z_q_st = zf + (zq - zf), accumulate loss numerator
__global__ __launch_bounds__(256) void k_out(const float* __restrict__ z,
                                             const float* __restrict__ cb,
                                             const float* __restrict__ m,
                                             const int* __restrict__ widx,
                                             float* __restrict__ out0,
                                             double* __restrict__ accs) {
    __shared__ float T[64 * 65];
    __shared__ float ls[4];
    int tid = threadIdx.x;
    int lhw = tid & 63, grp = tid >> 6;
    int bn = blockIdx.x >> 3, bc = blockIdx.x & 7;
    int n0 = bn * 64, c0 = bc * 64;
    int b = n0 >> 12, hw0 = n0 & 4095;
    const float* zb = z + (size_t)b * CCH * HW + hw0;
#pragma unroll
    for (int i = 0; i < 16; ++i) {
        int cl = grp + 4 * i;
        T[cl * 65 + lhw] = zb[(size_t)(c0 + cl) * HW + lhw];
    }
    __syncthreads();
    float la = 0.0f;
#pragma unroll
    for (int i = 0; i < 16; ++i) {
        int nl = grp + 4 * i;
        int n = n0 + nl;
        float zf = T[lhw * 65 + nl];
        int id = widx[n];
        float zq = cb[(size_t)id * CCH + c0 + lhw];
        float d = zq - zf;
        out0[(size_t)n * CCH + c0 + lhw] = zf + d;
        if (m[n] == 0.0f) la = fmaf(d, d, la);
    }
#pragma unroll
    for (int o = 32; o; o >>= 1) la += __shfl_xor(la, o);
    if ((tid & 63) == 0) ls[tid >> 6] = la;
    __syncthreads();
    if (tid == 0) atomicAdd(&accs[0], (double)(ls[0] + ls[1] + ls[2] + ls[3]));
}

// ---------------- K5: finalize loss = (1 + BETA) * mse
__global__ void k_final(const double* __restrict__ accs, float* __restrict__ outl) {
    double num = accs[0], wsum = accs[1];
    double denom = wsum * 512.0;
    double l1 = num / denom;
    outl[0] = (float)(l1 + 0.25 * l1);
}

extern "C" void kernel_launch(void* const* d_in, const int* in_sizes, int n_in,
                              void* d_out, int out_size, void* d_ws, size_t ws_size,
                              hipStream_t stream) {
    const float* z  = (const float*)d_in[0];
    const float* m  = (const float*)d_in[1];
    const float* cb = (const float*)d_in[2];
    float* out = (float*)d_out;
    char* ws = (char*)d_ws;

    float*  Bt   = (float*)(ws + WS_BT);
    float*  zzp  = (float*)(ws + WS_ZZ);
    int*    widx = (int*)(ws + WS_IDX);
    float*  wvH  = (float*)(ws + WS_WVH);
    int*    wiH  = (int*)(ws + WS_WIH);
    double* accs = (double*)(ws + WS_ACC);

    float* out0    = out;
    float* outLoss = out + 16777216;
    float* outIdx  = out + 16777217;

    hipLaunchKernelGGL(k_transpose, dim3(4096), dim3(256), 0, stream, cb, Bt, accs);
    hipLaunchKernelGGL(k_zz,        dim3(128),  dim3(256), 0, stream, z, zzp);
    hipLaunchKernelGGL(k_wsum,      dim3(32),   dim3(256), 0, stream, m, accs);
    hipLaunchKernelGGL(k_gemm,      dim3(1024), dim3(256), 0, stream, z, Bt, zzp, wvH, wiH);
    hipLaunchKernelGGL(k_merge,     dim3(128),  dim3(256), 0, stream, wvH, wiH, widx, outIdx);
    hipLaunchKernelGGL(k_out,       dim3(4096), dim3(256), 0, stream, z, cb, m, widx, out0, accs);
    hipLaunchKernelGGL(k_final,     dim3(1),    dim3(1),   0, stream, accs, outLoss);
}

// Round 5
// 1378.414 us; speedup vs baseline: 3.2619x; 2.5597x over previous
//
#include <hip/hip_runtime.h>
#include <math.h>

#define CCH 512
#define HW 4096
#define NN 32768
#define NE 8192

// ws layout (bytes)
#define WS_BT  0                         // BT bf16 hi/lo fragment-order: 8192*512*2 parts *2B = 16777216
#define WS_ZZ  (16777216)                // zz f32 [32768]
#define WS_BM1 (WS_ZZ + 131072)          // blockmax v1 [32768][64] f32 = 8388608
#define WS_BM2 (WS_BM1 + 8388608)        // blockmax v2 [32768][64] f32
#define WS_BI1 (WS_BM2 + 8388608)        // blockmax i1 [32768][64] i32
#define WS_IDX (WS_BI1 + 8388608)        // final idx [32768] i32
#define WS_ACC (WS_IDX + 131072)         // accs[0]=loss num, accs[1]=wsum (f64)

#define THRESH 3e-4f

typedef __attribute__((ext_vector_type(8)))  short short8;   // 8 bf16 (4 VGPRs)
typedef __attribute__((ext_vector_type(16))) float f32x16;   // 32x32 MFMA acc

// ---------------- K0: cb -> BT bf16 hi/lo, fragment-linear layout; zero accs
// chunk(jt32, s, part): 64 lanes x 16B; lane l holds cb[j=jt*32+(l&31)][k=s*16+(l>>5)*8 + e], e=0..7
__global__ __launch_bounds__(256) void k_prep_b(const float* __restrict__ cb,
                                                unsigned short* __restrict__ BT,
                                                double* __restrict__ accs) {
    int t = blockIdx.x * 256 + threadIdx.x;
    if (t == 0) { accs[0] = 0.0; accs[1] = 0.0; }
    int l = t & 63, s = (t >> 6) & 31, jt = t >> 11;
    int j = jt * 32 + (l & 31);
    int kb = s * 16 + (l >> 5) * 8;
    short8 hv, lv;
#pragma unroll
    for (int e = 0; e < 8; ++e) {
        float x = cb[(size_t)j * CCH + kb + e];
        unsigned u = __float_as_uint(x);
        hv[e] = (short)(u >> 16);                       // truncation: x - hi is exact
        float hf = __uint_as_float(u & 0xFFFF0000u);
        float lf = __fsub_rn(x, hf);
        lv[e] = (short)(__float_as_uint(lf) >> 16);
    }
    size_t chunk = ((size_t)jt * 32 + s) * 2;
    *(short8*)&BT[chunk * 512 + (size_t)l * 8] = hv;
    *(short8*)&BT[(chunk + 1) * 512 + (size_t)l * 8] = lv;
}

// ---------------- K1: zz[n] = np.sum(zf*zf, axis=1), numpy's exact pairwise tree
__global__ __launch_bounds__(256) void k_zz(const float* __restrict__ z,
                                            float* __restrict__ zz) {
    int t = threadIdx.x;
    int n = blockIdx.x * 256 + t;
    int b = n >> 12, hw = n & 4095;
    const float* zp = z + (size_t)b * CCH * HW + hw;
    float blk[4];
#pragma unroll
    for (int q = 0; q < 4; ++q) {
        float r[8];
#pragma unroll
        for (int j = 0; j < 8; ++j) {
            float v = zp[(size_t)(q * 128 + j) * HW];
            r[j] = __fmul_rn(v, v);
        }
        for (int i = 8; i < 128; i += 8) {
#pragma unroll
            for (int j = 0; j < 8; ++j) {
                float v = zp[(size_t)(q * 128 + i + j) * HW];
                r[j] = __fadd_rn(r[j], __fmul_rn(v, v));
            }
        }
        blk[q] = __fadd_rn(__fadd_rn(__fadd_rn(r[0], r[1]), __fadd_rn(r[2], r[3])),
                           __fadd_rn(__fadd_rn(r[4], r[5]), __fadd_rn(r[6], r[7])));
    }
    zz[n] = __fadd_rn(__fadd_rn(blk[0], blk[1]), __fadd_rn(blk[2], blk[3]));
}

// ---------------- K2: wsum = sum(m==0)
__global__ __launch_bounds__(256) void k_wsum(const float* __restrict__ m,
                                              double* __restrict__ accs) {
    __shared__ int sc[4];
    int tid = threadIdx.x;
    int base = blockIdx.x * 1024;
    int cnt = 0;
#pragma unroll
    for (int k2 = 0; k2 < 4; ++k2) cnt += (m[base + k2 * 256 + tid] == 0.0f) ? 1 : 0;
#pragma unroll
    for (int o = 32; o; o >>= 1) cnt += __shfl_xor(cnt, o);
    if ((tid & 63) == 0) sc[tid >> 6] = cnt;
    __syncthreads();
    if (tid == 0) atomicAdd(&accs[1], (double)(sc[0] + sc[1] + sc[2] + sc[3]));
}

// ---------------- K3: MFMA bf16-split GEMM. Block 128m x 128n, 4 waves (2x2), wave 64x64.
// S~ = hihi + hilo + lohi of (2z)·e. Per (row, nblock) store top-2 value + argmax index.
__global__ __launch_bounds__(256) void k_gemm(const float* __restrict__ z,
                                              const unsigned short* __restrict__ BT,
                                              float* __restrict__ bm1,
                                              float* __restrict__ bm2,
                                              int* __restrict__ bi1) {
    __shared__ char smem[32768];   // A dbuf 2x8KB @0, B dbuf 2x8KB @16384
    int tid = threadIdx.x;
    int l = tid & 63;
    int gq = tid >> 6;             // wave id = staging group (A mtile / B ntile)
    int wm = gq & 1, wn = gq >> 1;
    int nb = blockIdx.x & 63, mb = blockIdx.x >> 6;
    int khalf = l >> 5;

    // staging source pointers
    int m_glob = mb * 128 + gq * 32 + (l & 31);
    const float* zl = z + (size_t)(m_glob >> 12) * CCH * HW + (m_glob & 4095);

    f32x16 a00, a01, a10, a11;
#pragma unroll
    for (int i = 0; i < 16; ++i) { a00[i] = 0.f; a01[i] = 0.f; a10[i] = 0.f; a11[i] = 0.f; }

    float av[8];
    uint4 bv0, bv1;

#define LOADSTEP(S) do { \
    int kb_ = (S) * 16 + khalf * 8; \
    _Pragma("unroll") for (int e = 0; e < 8; ++e) av[e] = zl[(size_t)(kb_ + e) * HW]; \
    size_t bgi_ = ((((size_t)nb * 4 + gq) * 32 + (S)) * 2) * 512 + (size_t)l * 8; \
    bv0 = *(const uint4*)&BT[bgi_]; bv1 = *(const uint4*)&BT[bgi_ + 512]; \
} while (0)

#define WRITESTEP(BUF) do { \
    short8 hv_, lv_; \
    _Pragma("unroll") for (int e = 0; e < 8; ++e) { \
        float x_ = 2.0f * av[e]; \
        unsigned u_ = __float_as_uint(x_); \
        hv_[e] = (short)(u_ >> 16); \
        float hf_ = __uint_as_float(u_ & 0xFFFF0000u); \
        float lf_ = __fsub_rn(x_, hf_); \
        lv_[e] = (short)(__float_as_uint(lf_) >> 16); \
    } \
    int ab_ = (BUF) * 8192, bb_ = 16384 + (BUF) * 8192; \
    *(short8*)&smem[ab_ + (gq * 2 + 0) * 1024 + l * 16] = hv_; \
    *(short8*)&smem[ab_ + (gq * 2 + 1) * 1024 + l * 16] = lv_; \
    *(uint4*)&smem[bb_ + (gq * 2 + 0) * 1024 + l * 16] = bv0; \
    *(uint4*)&smem[bb_ + (gq * 2 + 1) * 1024 + l * 16] = bv1; \
} while (0)

    LOADSTEP(0);
    WRITESTEP(0);
    __syncthreads();

    for (int s = 0; s < 32; ++s) {
        if (s < 31) LOADSTEP(s + 1);
        int ab = (s & 1) * 8192, bb = 16384 + (s & 1) * 8192;
        short8 ah0 = *(short8*)&smem[ab + ((wm * 2 + 0) * 2 + 0) * 1024 + l * 16];
        short8 al0 = *(short8*)&smem[ab + ((wm * 2 + 0) * 2 + 1) * 1024 + l * 16];
        short8 ah1 = *(short8*)&smem[ab + ((wm * 2 + 1) * 2 + 0) * 1024 + l * 16];
        short8 al1 = *(short8*)&smem[ab + ((wm * 2 + 1) * 2 + 1) * 1024 + l * 16];
        short8 bh0 = *(short8*)&smem[bb + ((wn * 2 + 0) * 2 + 0) * 1024 + l * 16];
        short8 bl0 = *(short8*)&smem[bb + ((wn * 2 + 0) * 2 + 1) * 1024 + l * 16];
        short8 bh1 = *(short8*)&smem[bb + ((wn * 2 + 1) * 2 + 0) * 1024 + l * 16];
        short8 bl1 = *(short8*)&smem[bb + ((wn * 2 + 1) * 2 + 1) * 1024 + l * 16];
        a00 = __builtin_amdgcn_mfma_f32_32x32x16_bf16(ah0, bh0, a00, 0, 0, 0);
        a00 = __builtin_amdgcn_mfma_f32_32x32x16_bf16(ah0, bl0, a00, 0, 0, 0);
        a00 = __builtin_amdgcn_mfma_f32_32x32x16_bf16(al0, bh0, a00, 0, 0, 0);
        a01 = __builtin_amdgcn_mfma_f32_32x32x16_bf16(ah0, bh1, a01, 0, 0, 0);
        a01 = __builtin_amdgcn_mfma_f32_32x32x16_bf16(ah0, bl1, a01, 0, 0, 0);
        a01 = __builtin_amdgcn_mfma_f32_32x32x16_bf16(al0, bh1, a01, 0, 0, 0);
        a10 = __builtin_amdgcn_mfma_f32_32x32x16_bf16(ah1, bh0, a10, 0, 0, 0);
        a10 = __builtin_amdgcn_mfma_f32_32x32x16_bf16(ah1, bl0, a10, 0, 0, 0);
        a10 = __builtin_amdgcn_mfma_f32_32x32x16_bf16(al1, bh0, a10, 0, 0, 0);
        a11 = __builtin_amdgcn_mfma_f32_32x32x16_bf16(ah1, bh1, a11, 0, 0, 0);
        a11 = __builtin_amdgcn_mfma_f32_32x32x16_bf16(ah1, bl1, a11, 0, 0, 0);
        a11 = __builtin_amdgcn_mfma_f32_32x32x16_bf16(al1, bh1, a11, 0, 0, 0);
        if (s < 31) {
            WRITESTEP((s + 1) & 1);
            __syncthreads();
        }
    }

    // Epilogue: per (row, this block's 128 j) top-2 + argmax.
    // D layout: col(j) = lane&31, row = (r&3) + 8*(r>>2) + 4*(lane>>5).
    float* ev1 = (float*)smem;            // [128 rows][2 wn]
    float* ev2 = (float*)(smem + 2048);
    int*   ei1 = (int*)(smem + 4096);
    int ja_base = nb * 128 + wn * 64 + (l & 31);
#pragma unroll
    for (int mtl = 0; mtl < 2; ++mtl) {
        const f32x16& t0 = mtl ? a10 : a00;
        const f32x16& t1 = mtl ? a11 : a01;
#pragma unroll
        for (int r = 0; r < 16; ++r) {
            float va = t0[r], vb = t1[r];
            int ja = ja_base, jb = ja_base + 32;
            float v1, v2; int i1;
            if (vb > va) { v1 = vb; i1 = jb; v2 = va; }
            else         { v1 = va; i1 = ja; v2 = vb; }
#pragma unroll
            for (int o = 1; o <= 16; o <<= 1) {
                float o1 = __shfl_xor(v1, o);
                float o2 = __shfl_xor(v2, o);
                int   oi = __shfl_xor(i1, o);
                if (o1 > v1) { v2 = fmaxf(v1, o2); v1 = o1; i1 = oi; }
                else         { v2 = fmaxf(v2, o1); }
            }
            if ((l & 31) == r) {
                int rl = wm * 64 + mtl * 32 + (r & 3) + 8 * (r >> 2) + 4 * khalf;
                ev1[rl * 2 + wn] = v1;
                ev2[rl * 2 + wn] = v2;
                ei1[rl * 2 + wn] = i1;
            }
        }
    }
    __syncthreads();
    if (tid < 128) {
        float p1 = ev1[tid * 2 + 0], p2 = ev2[tid * 2 + 0];
        int   pi = ei1[tid * 2 + 0];
        float q1 = ev1[tid * 2 + 1], q2 = ev2[tid * 2 + 1];
        int   qi = ei1[tid * 2 + 1];
        float v1, v2; int i1;
        if (q1 > p1) { v1 = q1; i1 = qi; v2 = fmaxf(p1, q2); }
        else         { v1 = p1; i1 = pi; v2 = fmaxf(q1, p2); }
        size_t rowg = (size_t)mb * 128 + tid;
        bm1[rowg * 64 + nb] = v1;
        bm2[rowg * 64 + nb] = v2;
        bi1[rowg * 64 + nb] = i1;
    }
}

// ---------------- K4: exact fp32-chain rescan of candidates; writes idx (bit-exact np argmin)
__global__ __launch_bounds__(64) void k_rescan(const float* __restrict__ z,
                                               const float* __restrict__ cb,
                                               const float* __restrict__ zz,
                                               const float* __restrict__ bm1,
                                               const float* __restrict__ bm2,
                                               const int* __restrict__ bi1,
                                               int* __restrict__ widx,
                                               float* __restrict__ out_idx) {
    __shared__ float a2[512];
    int row = blockIdx.x;
    int t = threadIdx.x;
    float v1 = bm1[(size_t)row * 64 + t];
    float v2 = bm2[(size_t)row * 64 + t];
    int   i1 = bi1[(size_t)row * 64 + t];
    float M = v1;
#pragma unroll
    for (int o = 1; o <= 32; o <<= 1) M = fmaxf(M, __shfl_xor(M, o));
    float th = M - THRESH;

    const float* zp = z + (size_t)(row >> 12) * CCH * HW + (row & 4095);
    for (int k = t; k < 512; k += 64) a2[k] = 2.0f * zp[(size_t)k * HW];
    float zzv = zz[row];
    __syncthreads();

    float bC = 3.0e38f;
    int bj = 0x7FFFFFFF;
    bool fullF = (v2 >= th);
    if (v1 >= th && !fullF) {
        const float* cr = cb + (size_t)i1 * CCH;
        float acc = 0.0f;
        for (int k = 0; k < 512; ++k) acc = __fmaf_rn(a2[k], cr[k], acc);
        bC = __fsub_rn(zzv, acc);
        bj = i1;
    }
    unsigned long long fm = __ballot(fullF);
    while (fm) {
        int nb2 = __ffsll(fm) - 1;
        fm &= fm - 1;
#pragma unroll
        for (int h = 0; h < 2; ++h) {
            int j = nb2 * 128 + h * 64 + t;
            const float* cr = cb + (size_t)j * CCH;
            float acc = 0.0f;
            for (int k = 0; k < 512; ++k) acc = __fmaf_rn(a2[k], cr[k], acc);
            float C = __fsub_rn(zzv, acc);
            if (C < bC || (C == bC && j < bj)) { bC = C; bj = j; }
        }
    }
#pragma unroll
    for (int o = 1; o <= 32; o <<= 1) {
        float oC = __shfl_xor(bC, o);
        int   oj = __shfl_xor(bj, o);
        if (oC < bC || (oC == bC && oj < bj)) { bC = oC; bj = oj; }
    }
    if (t == 0) { widx[row] = bj; out_idx[row] = (float)bj; }
}

// ---------------- K5: gather z_q, write z_q_st, accumulate loss numerator
__global__ __launch_bounds__(256) void k_out(const float* __restrict__ z,
                                             const float* __restrict__ cb,
                                             const float* __restrict__ m,
                                             const int* __restrict__ widx,
                                             float* __restrict__ out0,
                                             double* __restrict__ accs) {
    __shared__ float T[64 * 65];
    __shared__ float ls[4];
    int tid = threadIdx.x;
    int lhw = tid & 63, grp = tid >> 6;
    int bn = blockIdx.x >> 3, bc = blockIdx.x & 7;
    int n0 = bn * 64, c0 = bc * 64;
    int b = n0 >> 12, hw0 = n0 & 4095;
    const float* zb = z + (size_t)b * CCH * HW + hw0;
#pragma unroll
    for (int i = 0; i < 16; ++i) {
        int cl = grp + 4 * i;
        T[cl * 65 + lhw] = zb[(size_t)(c0 + cl) * HW + lhw];
    }
    __syncthreads();
    float la = 0.0f;
#pragma unroll
    for (int i = 0; i < 16; ++i) {
        int nl = grp + 4 * i;
        int n = n0 + nl;
        float zf = T[lhw * 65 + nl];
        int id = widx[n];
        float zq = cb[(size_t)id * CCH + c0 + lhw];
        float d = zq - zf;
        out0[(size_t)n * CCH + c0 + lhw] = zf + d;
        if (m[n] == 0.0f) la = fmaf(d, d, la);
    }
#pragma unroll
    for (int o = 32; o; o >>= 1) la += __shfl_xor(la, o);
    if ((tid & 63) == 0) ls[tid >> 6] = la;
    __syncthreads();
    if (tid == 0) atomicAdd(&accs[0], (double)(ls[0] + ls[1] + ls[2] + ls[3]));
}

// ---------------- K6: finalize loss = (1 + BETA) * mse
__global__ void k_final(const double* __restrict__ accs, float* __restrict__ outl) {
    double num = accs[0], wsum = accs[1];
    double denom = wsum * 512.0;
    double l1 = num / denom;
    outl[0] = (float)(l1 + 0.25 * l1);
}

extern "C" void kernel_launch(void* const* d_in, const int* in_sizes, int n_in,
                              void* d_out, int out_size, void* d_ws, size_t ws_size,
                              hipStream_t stream) {
    const float* z  = (const float*)d_in[0];
    const float* m  = (const float*)d_in[1];
    const float* cb = (const float*)d_in[2];
    float* out = (float*)d_out;
    char* ws = (char*)d_ws;

    unsigned short* BT   = (unsigned short*)(ws + WS_BT);
    float*  zzp  = (float*)(ws + WS_ZZ);
    float*  bm1  = (float*)(ws + WS_BM1);
    float*  bm2  = (float*)(ws + WS_BM2);
    int*    bi1  = (int*)(ws + WS_BI1);
    int*    widx = (int*)(ws + WS_IDX);
    double* accs = (double*)(ws + WS_ACC);

    float* out0    = out;
    float* outLoss = out + 16777216;
    float* outIdx  = out + 16777217;

    hipLaunchKernelGGL(k_prep_b, dim3(2048), dim3(256), 0, stream, cb, BT, accs);
    hipLaunchKernelGGL(k_zz,     dim3(128),  dim3(256), 0, stream, z, zzp);
    hipLaunchKernelGGL(k_wsum,   dim3(32),   dim3(256), 0, stream, m, accs);
    hipLaunchKernelGGL(k_gemm,   dim3(16384), dim3(256), 0, stream, z, BT, bm1, bm2, bi1);
    hipLaunchKernelGGL(k_rescan, dim3(32768), dim3(64), 0, stream, z, cb, zzp, bm1, bm2, bi1, widx, outIdx);
    hipLaunchKernelGGL(k_out,    dim3(4096), dim3(256), 0, stream, z, cb, m, widx, out0, accs);
    hipLaunchKernelGGL(k_final,  dim3(1),    dim3(1),   0, stream, accs, outLoss);
}